// Round 5
// baseline (289.978 us; speedup 1.0000x reference)
//
#include <hip/hip_runtime.h>

typedef __attribute__((ext_vector_type(8))) short short8;   // 8 bf16 = 4 VGPRs
typedef __attribute__((ext_vector_type(4))) float floatx4;  // MFMA acc

typedef __attribute__((address_space(3))) unsigned int lds_u32;
typedef __attribute__((address_space(1))) const unsigned int glb_u32;

#define NBLK 512

static __device__ __forceinline__ unsigned short f2bf(float f) {
    unsigned int u = __float_as_uint(f);
    return (unsigned short)((u + 0x7FFFu + ((u >> 16) & 1u)) >> 16);   // RNE
}
static __device__ __forceinline__ void cp16(const ushort* g, ushort* l) {
    __builtin_amdgcn_global_load_lds((glb_u32*)g, (lds_u32*)l, 16, 0, 0);
}

// Single persistent kernel: prep -> [gather overlapped with grid barrier 1] ->
// conv1 -> grid barrier 2 -> conv2 + dur head. 512 blocks, 2/CU co-resident.
__global__ __launch_bounds__(256, 2)
void fused_kernel(const float* __restrict__ x, const int* __restrict__ target,
                  const float* __restrict__ w1, const float* __restrict__ c1b,
                  const float* __restrict__ g1, const float* __restrict__ b1,
                  const float* __restrict__ w2, const float* __restrict__ c2b,
                  const float* __restrict__ g2, const float* __restrict__ b2,
                  const float* __restrict__ lw, const float* __restrict__ lb,
                  ushort* __restrict__ xb, ushort* __restrict__ h1b,
                  ushort* __restrict__ w1pb, ushort* __restrict__ w2pb,
                  unsigned* __restrict__ bars,
                  float* __restrict__ out0, float* __restrict__ durp)
{
    __shared__ ushort As[32 * 64];    // 4 KB, quad-swizzled
    __shared__ ushort Bs[256 * 64];   // 32 KB, quad-swizzled (aliased by scan bufs)
    __shared__ float sum_s[4][32], sq_s[4][32], mu_s[32], rs_s[32];

    const int tid = threadIdx.x, blk = blockIdx.x;

    // ---------------- phase 0a: x -> bf16 padded [B][514][256] ----------------
    for (int u = blk; u < 4112; u += NBLK) {
        const int r = u * 4 + (tid >> 6);
        const int c = (tid & 63) * 4;
        const int b = r / 514, tp = r % 514;
        ushort4 o;
        if (tp >= 1 && tp <= 512) {
            float4 v = *(const float4*)(x + ((size_t)(b * 512 + tp - 1) * 256 + c));
            o.x = f2bf(v.x); o.y = f2bf(v.y); o.z = f2bf(v.z); o.w = f2bf(v.w);
        } else {
            o.x = o.y = o.z = o.w = 0;
            *(ushort4*)(h1b + (size_t)r * 256 + c) = o;   // zero h1b pad rows
        }
        *(ushort4*)(xb + (size_t)r * 256 + c) = o;
    }
    // ---------------- phase 0b: weight repack (swizzled [12][256][64]) --------
    for (int u = blk; u < 1536; u += NBLK) {
        const bool second = u >= 768;
        const int e = (u - (second ? 768 : 0)) * 256 + tid;
        const float* w = second ? w2 : w1;
        ushort* wpb = second ? w2pb : w1pb;
        const int f = e / 768, j = e % 768;
        const int c = j & 255, kr = j >> 8;
        wpb[(j >> 6) * 16384 + f * 64 + ((((j & 63) >> 3) ^ (f & 7)) << 3) + (j & 7)]
            = f2bf(w[f * 768 + c * 3 + kr]);
    }

    // -------- barrier 1 ARRIVE (xb/h1b-pad/wpb published) --------
    __syncthreads();                               // drains vmcnt per wave
    if (tid == 0) {
        __threadfence();
        __hip_atomic_fetch_add(&bars[0], 1u, __ATOMIC_RELEASE, __HIP_MEMORY_SCOPE_AGENT);
    }

    // ---------------- phase 0c: scan + gather (inputs only; overlaps b1) -----
    {
        int* cum  = (int*)Bs;          // alias: Bs unused until conv1
        int* ps   = cum + 512;
        int* sidx = ps + 256;
        const int gb = blk >> 4, gseg = blk & 15;
        const int v0 = target[gb * 512 + 2 * tid];
        const int v1 = target[gb * 512 + 2 * tid + 1];
        ps[tid] = v0 + v1;
        __syncthreads();
        for (int off = 1; off < 256; off <<= 1) {
            int t = (tid >= off) ? ps[tid - off] : 0;
            __syncthreads();
            ps[tid] += t;
            __syncthreads();
        }
        const int excl = tid ? ps[tid - 1] : 0;
        cum[2 * tid]     = excl + v0;
        cum[2 * tid + 1] = excl + v0 + v1;
        __syncthreads();
        const int total = cum[511];
        if (tid < 144) {
            int t = gseg * 144 + tid;
            int lo = 0, hi = 512;
            while (lo < hi) {
                int mid = (lo + hi) >> 1;
                if (cum[mid] <= t) lo = mid + 1; else hi = mid;
            }
            sidx[tid] = (t < total) ? ((lo < 512) ? lo : 511) : -1;
        }
        __syncthreads();
        const float4* x4 = (const float4*)x;
        float4* o4 = (float4*)out0;
        const int lane6 = tid & 63, g4 = tid >> 6;
        #pragma unroll 4
        for (int it = 0; it < 36; ++it) {
            int r = it * 4 + g4;
            int idx = sidx[r];
            float4 v = make_float4(0.f, 0.f, 0.f, 0.f);
            if (idx >= 0) v = x4[((size_t)(gb * 512 + idx)) * 64 + lane6];
            o4[((size_t)(gb * 2304 + gseg * 144 + r)) * 64 + lane6] = v;
        }
    }

    // -------- barrier 1 WAIT --------
    if (tid == 0)
        while (__hip_atomic_load(&bars[0], __ATOMIC_ACQUIRE,
                                 __HIP_MEMORY_SCOPE_AGENT) < NBLK)
            __builtin_amdgcn_s_sleep(2);
    __syncthreads();

    // ---------------- conv setup (shared by both convs) ----------------
    const int w_ = tid >> 6, lane = tid & 63;
    const int q = lane >> 4, col = lane & 15;
    const int cbk_b = blk >> 4, t0 = (blk & 15) << 5;
    const int arow = tid >> 3, aquad = (tid & 7) ^ (arow & 7);
    ushort* AsW = As + (size_t)w_ * 512;
    ushort* BsW = Bs + (size_t)w_ * 512;
    const int base_c = w_ * 64;

    // =========================== conv1: xb -> h1b ===========================
    {
        floatx4 acc[2][4] = {};
        const ushort* inb = xb + (size_t)cbk_b * 514 * 256;
        for (int s = 0; s < 12; ++s) {
            const int krow = s >> 2, cbo = (s & 3) << 6;
            cp16(inb + (size_t)(t0 + krow + arow) * 256 + cbo + aquad * 8, AsW);
            const ushort* wsrc = w1pb + (size_t)s * 16384 + w_ * 512 + lane * 8;
            #pragma unroll
            for (int i = 0; i < 8; ++i) cp16(wsrc + i * 2048, BsW + i * 2048);
            __syncthreads();
            short8 af[2][2], bf[4][2];
            #pragma unroll
            for (int mi = 0; mi < 2; ++mi)
                #pragma unroll
                for (int kh = 0; kh < 2; ++kh)
                    af[mi][kh] = *(const short8*)((const char*)As
                        + (mi * 16 + col) * 128 + (((kh * 4 + q) ^ (col & 7)) * 16));
            #pragma unroll
            for (int ni = 0; ni < 4; ++ni)
                #pragma unroll
                for (int kh = 0; kh < 2; ++kh)
                    bf[ni][kh] = *(const short8*)((const char*)Bs
                        + (w_ * 64 + ni * 16 + col) * 128 + (((kh * 4 + q) ^ (col & 7)) * 16));
            #pragma unroll
            for (int kh = 0; kh < 2; ++kh)
                #pragma unroll
                for (int mi = 0; mi < 2; ++mi)
                    #pragma unroll
                    for (int ni = 0; ni < 4; ++ni)
                        acc[mi][ni] = __builtin_amdgcn_mfma_f32_16x16x32_bf16(
                            af[mi][kh], bf[ni][kh], acc[mi][ni], 0, 0, 0);
            __syncthreads();
        }
        // epilogue: bias + LN + ReLU -> h1b (bf16)
        float cb4[4], gm4[4], bt4[4];
        #pragma unroll
        for (int ni = 0; ni < 4; ++ni) {
            cb4[ni] = c1b[base_c + ni * 16 + col];
            gm4[ni] = g1 [base_c + ni * 16 + col];
            bt4[ni] = b1 [base_c + ni * 16 + col];
        }
        float rsum[2][4] = {}, rsq[2][4] = {};
        #pragma unroll
        for (int mi = 0; mi < 2; ++mi)
            #pragma unroll
            for (int ni = 0; ni < 4; ++ni)
                #pragma unroll
                for (int r = 0; r < 4; ++r) {
                    float v = acc[mi][ni][r] + cb4[ni];
                    acc[mi][ni][r] = v;
                    rsum[mi][r] += v; rsq[mi][r] += v * v;
                }
        #pragma unroll
        for (int mi = 0; mi < 2; ++mi)
            #pragma unroll
            for (int r = 0; r < 4; ++r) {
                float s = rsum[mi][r], ss = rsq[mi][r];
                #pragma unroll
                for (int d = 8; d > 0; d >>= 1) {
                    s += __shfl_down(s, d, 16); ss += __shfl_down(ss, d, 16);
                }
                if (col == 0) {
                    sum_s[w_][mi * 16 + q * 4 + r] = s;
                    sq_s [w_][mi * 16 + q * 4 + r] = ss;
                }
            }
        __syncthreads();
        if (tid < 32) {
            float s  = sum_s[0][tid] + sum_s[1][tid] + sum_s[2][tid] + sum_s[3][tid];
            float ss = sq_s [0][tid] + sq_s [1][tid] + sq_s [2][tid] + sq_s [3][tid];
            float mu = s * (1.f / 256.f);
            mu_s[tid] = mu;
            rs_s[tid] = rsqrtf(ss * (1.f / 256.f) - mu * mu + 1e-5f);
        }
        __syncthreads();
        #pragma unroll
        for (int mi = 0; mi < 2; ++mi)
            #pragma unroll
            for (int ni = 0; ni < 4; ++ni)
                #pragma unroll
                for (int r = 0; r < 4; ++r) {
                    int row = mi * 16 + q * 4 + r;
                    float v = (acc[mi][ni][r] - mu_s[row]) * rs_s[row] * gm4[ni] + bt4[ni];
                    h1b[((size_t)cbk_b * 514 + t0 + row + 1) * 256 + base_c + ni * 16 + col]
                        = f2bf(fmaxf(v, 0.f));
                }
    }

    // -------- barrier 2 (h1b published) --------
    __syncthreads();
    if (tid == 0) {
        __threadfence();
        __hip_atomic_fetch_add(&bars[1], 1u, __ATOMIC_RELEASE, __HIP_MEMORY_SCOPE_AGENT);
        while (__hip_atomic_load(&bars[1], __ATOMIC_ACQUIRE,
                                 __HIP_MEMORY_SCOPE_AGENT) < NBLK)
            __builtin_amdgcn_s_sleep(2);
    }
    __syncthreads();

    // ================== conv2: h1b -> LN -> ReLU -> dur head ==================
    {
        floatx4 acc[2][4] = {};
        const ushort* inb = h1b + (size_t)cbk_b * 514 * 256;
        for (int s = 0; s < 12; ++s) {
            const int krow = s >> 2, cbo = (s & 3) << 6;
            cp16(inb + (size_t)(t0 + krow + arow) * 256 + cbo + aquad * 8, AsW);
            const ushort* wsrc = w2pb + (size_t)s * 16384 + w_ * 512 + lane * 8;
            #pragma unroll
            for (int i = 0; i < 8; ++i) cp16(wsrc + i * 2048, BsW + i * 2048);
            __syncthreads();
            short8 af[2][2], bf[4][2];
            #pragma unroll
            for (int mi = 0; mi < 2; ++mi)
                #pragma unroll
                for (int kh = 0; kh < 2; ++kh)
                    af[mi][kh] = *(const short8*)((const char*)As
                        + (mi * 16 + col) * 128 + (((kh * 4 + q) ^ (col & 7)) * 16));
            #pragma unroll
            for (int ni = 0; ni < 4; ++ni)
                #pragma unroll
                for (int kh = 0; kh < 2; ++kh)
                    bf[ni][kh] = *(const short8*)((const char*)Bs
                        + (w_ * 64 + ni * 16 + col) * 128 + (((kh * 4 + q) ^ (col & 7)) * 16));
            #pragma unroll
            for (int kh = 0; kh < 2; ++kh)
                #pragma unroll
                for (int mi = 0; mi < 2; ++mi)
                    #pragma unroll
                    for (int ni = 0; ni < 4; ++ni)
                        acc[mi][ni] = __builtin_amdgcn_mfma_f32_16x16x32_bf16(
                            af[mi][kh], bf[ni][kh], acc[mi][ni], 0, 0, 0);
            __syncthreads();
        }
        float cb4[4], gm4[4], bt4[4], lw4[4];
        #pragma unroll
        for (int ni = 0; ni < 4; ++ni) {
            cb4[ni] = c2b[base_c + ni * 16 + col];
            gm4[ni] = g2 [base_c + ni * 16 + col];
            bt4[ni] = b2 [base_c + ni * 16 + col];
            lw4[ni] = lw [base_c + ni * 16 + col];
        }
        float rsum[2][4] = {}, rsq[2][4] = {};
        #pragma unroll
        for (int mi = 0; mi < 2; ++mi)
            #pragma unroll
            for (int ni = 0; ni < 4; ++ni)
                #pragma unroll
                for (int r = 0; r < 4; ++r) {
                    float v = acc[mi][ni][r] + cb4[ni];
                    acc[mi][ni][r] = v;
                    rsum[mi][r] += v; rsq[mi][r] += v * v;
                }
        #pragma unroll
        for (int mi = 0; mi < 2; ++mi)
            #pragma unroll
            for (int r = 0; r < 4; ++r) {
                float s = rsum[mi][r], ss = rsq[mi][r];
                #pragma unroll
                for (int d = 8; d > 0; d >>= 1) {
                    s += __shfl_down(s, d, 16); ss += __shfl_down(ss, d, 16);
                }
                if (col == 0) {
                    sum_s[w_][mi * 16 + q * 4 + r] = s;
                    sq_s [w_][mi * 16 + q * 4 + r] = ss;
                }
            }
        __syncthreads();
        if (tid < 32) {
            float s  = sum_s[0][tid] + sum_s[1][tid] + sum_s[2][tid] + sum_s[3][tid];
            float ss = sq_s [0][tid] + sq_s [1][tid] + sq_s [2][tid] + sq_s [3][tid];
            float mu = s * (1.f / 256.f);
            mu_s[tid] = mu;
            rs_s[tid] = rsqrtf(ss * (1.f / 256.f) - mu * mu + 1e-5f);
        }
        __syncthreads();
        float dsum[2][4] = {};
        #pragma unroll
        for (int mi = 0; mi < 2; ++mi)
            #pragma unroll
            for (int ni = 0; ni < 4; ++ni)
                #pragma unroll
                for (int r = 0; r < 4; ++r) {
                    int row = mi * 16 + q * 4 + r;
                    float v = (acc[mi][ni][r] - mu_s[row]) * rs_s[row] * gm4[ni] + bt4[ni];
                    dsum[mi][r] += fmaxf(v, 0.f) * lw4[ni];
                }
        #pragma unroll
        for (int mi = 0; mi < 2; ++mi)
            #pragma unroll
            for (int r = 0; r < 4; ++r) {
                float s = dsum[mi][r];
                #pragma unroll
                for (int d = 8; d > 0; d >>= 1) s += __shfl_down(s, d, 16);
                if (col == 0) sum_s[w_][mi * 16 + q * 4 + r] = s;
            }
        __syncthreads();
        if (tid < 32)
            durp[cbk_b * 512 + t0 + tid] = fmaxf(sum_s[0][tid] + sum_s[1][tid]
                                               + sum_s[2][tid] + sum_s[3][tid] + lb[0], 0.f);
    }
}

extern "C" void kernel_launch(void* const* d_in, const int* in_sizes, int n_in,
                              void* d_out, int out_size, void* d_ws, size_t ws_size,
                              hipStream_t stream) {
    const float* x      = (const float*)d_in[0];
    const int*   target = (const int*)  d_in[1];
    const float* c1w = (const float*)d_in[3];
    const float* c1b = (const float*)d_in[4];
    const float* g1  = (const float*)d_in[5];
    const float* b1  = (const float*)d_in[6];
    const float* c2w = (const float*)d_in[7];
    const float* c2b = (const float*)d_in[8];
    const float* g2  = (const float*)d_in[9];
    const float* b2  = (const float*)d_in[10];
    const float* lw  = (const float*)d_in[11];
    const float* lb  = (const float*)d_in[12];

    const size_t PADEL = (size_t)32 * 514 * 256;   // 4,210,688 ushorts
    ushort* xb   = (ushort*)d_ws;
    ushort* h1b  = xb + PADEL;
    ushort* w1pb = h1b + PADEL;
    ushort* w2pb = w1pb + 196608;
    unsigned* bars = (unsigned*)(w2pb + 196608);   // byte offset 17,629,184 (64B-aligned)

    float* out0 = (float*)d_out;                   // [32, 2304, 256]
    float* durp = out0 + (size_t)32 * 2304 * 256;  // [32, 512]

    hipMemsetAsync(bars, 0, 16, stream);           // zero barrier counters (capture-legal)
    fused_kernel<<<NBLK, 256, 0, stream>>>(
        x, target, c1w, c1b, g1, b1, c2w, c2b, g2, b2, lw, lb,
        xb, h1b, w1pb, w2pb, bars, out0, durp);
}

// Round 6
// 168.571 us; speedup vs baseline: 1.7202x; 1.7202x over previous
//
#include <hip/hip_runtime.h>

typedef __attribute__((ext_vector_type(8))) short short8;   // 8 bf16 = 4 VGPRs
typedef __attribute__((ext_vector_type(4))) float floatx4;  // MFMA acc

typedef __attribute__((address_space(3))) unsigned int lds_u32;
typedef __attribute__((address_space(1))) const unsigned int glb_u32;

static __device__ __forceinline__ unsigned short f2bf(float f) {
    unsigned int u = __float_as_uint(f);
    return (unsigned short)((u + 0x7FFFu + ((u >> 16) & 1u)) >> 16);   // RNE
}
// async 16-B global->LDS DMA; LDS dest = wave-uniform base + lane*16
static __device__ __forceinline__ void cp16(const ushort* g, ushort* l) {
    __builtin_amdgcn_global_load_lds((glb_u32*)g, (lds_u32*)l, 16, 0, 0);
}

// ---- prep: x->bf16 padded [B][514][256]; w[F][C][3] -> swizzled [12][256][64] ----
// blocks [0,4112): x-convert;  [4112,4880): w1;  [4880,5648): w2
__global__ __launch_bounds__(256)
void prep_kernel(const float* __restrict__ x, const float* __restrict__ w1,
                 const float* __restrict__ w2,
                 ushort* __restrict__ xb, ushort* __restrict__ h1b,
                 ushort* __restrict__ w1pb, ushort* __restrict__ w2pb)
{
    const int blk = blockIdx.x, tid = threadIdx.x;
    if (blk < 4112) {
        const int r = blk * 4 + (tid >> 6);
        const int c = (tid & 63) * 4;
        const int b = r / 514, tp = r % 514;
        ushort4 o;
        if (tp >= 1 && tp <= 512) {
            float4 v = *(const float4*)(x + ((size_t)(b * 512 + tp - 1) * 256 + c));
            o.x = f2bf(v.x); o.y = f2bf(v.y); o.z = f2bf(v.z); o.w = f2bf(v.w);
        } else {
            o.x = o.y = o.z = o.w = 0;
            *(ushort4*)(h1b + (size_t)r * 256 + c) = o;   // zero h1b pad rows
        }
        *(ushort4*)(xb + (size_t)r * 256 + c) = o;
    } else {
        const bool second = blk >= 4880;
        const int e = (blk - (second ? 4880 : 4112)) * 256 + tid;
        const float* w = second ? w2 : w1;
        ushort* wpb = second ? w2pb : w1pb;
        const int f = e / 768, j = e % 768;
        const int c = j & 255, kr = j >> 8;
        const int s = j >> 6, kk = j & 63;
        wpb[s * 16384 + f * 64 + (((kk >> 3) ^ (f & 7)) << 3) + (kk & 7)]
            = f2bf(w[f * 768 + c * 3 + kr]);
    }
}

// ---- conv1d(K=3) MFMA GEMM: barrier-free per-wave pipelined K-loop ----
// Grid: 512 conv blocks (+1152 gather blocks when IS_CONV2). Block 256 (4 waves).
// Block tile 32 rows x 256 cols; wave w owns cols [w*64,(w+1)*64). K=768 in 12x64.
// Per-wave double-buffered LDS B (2x8 KB); A frags direct global->VGPR.
// NO s_barrier in the K-loop: per-wave s_waitcnt vmcnt(12) keeps the step-(s+1)
// prefetch (8 DMA + 4 A-loads = 12 ops) in flight while step s computes.
template<bool IS_CONV2>
__global__ __launch_bounds__(256, 2)
void conv_mfma_kernel(const ushort* __restrict__ xb,   // [B][514][256] bf16 padded
                      const ushort* __restrict__ wpb,  // [12][256][64] bf16 swizzled
                      const float* __restrict__ cbias,
                      const float* __restrict__ gamma, const float* __restrict__ beta,
                      const float* __restrict__ lw, const float* __restrict__ lb,
                      ushort* __restrict__ outb,       // conv1: h1b
                      float* __restrict__ durp,        // conv2: [B][512]
                      const float* __restrict__ x,     // conv2 gather path
                      const int* __restrict__ target,
                      float* __restrict__ out0)        // [B][2304][256]
{
    __shared__ ushort Bws[4][2][4096];                 // 64 KB: per-wave dbuf B
    __shared__ float sum_s[4][32], sq_s[4][32], mu_s[32], rs_s[32];
    __shared__ int cum[512], ps[256], sidx[64];        // gather path only

    const int tid = threadIdx.x;

    if (IS_CONV2 && blockIdx.x >= 512) {
        // ---------- gather: 1152 blocks, 64 output rows each ----------
        const int bg = blockIdx.x - 512;
        const int b = bg / 36, t0o = (bg % 36) * 64;
        const int v0 = target[b * 512 + 2 * tid];
        const int v1 = target[b * 512 + 2 * tid + 1];
        ps[tid] = v0 + v1;
        __syncthreads();
        for (int off = 1; off < 256; off <<= 1) {
            int t = (tid >= off) ? ps[tid - off] : 0;
            __syncthreads();
            ps[tid] += t;
            __syncthreads();
        }
        const int excl = tid ? ps[tid - 1] : 0;
        cum[2 * tid]     = excl + v0;
        cum[2 * tid + 1] = excl + v0 + v1;
        __syncthreads();
        const int total = cum[511];
        if (tid < 64) {
            int t = t0o + tid;
            int lo = 0, hi = 512;
            while (lo < hi) {
                int mid = (lo + hi) >> 1;
                if (cum[mid] <= t) lo = mid + 1; else hi = mid;
            }
            sidx[tid] = (t < total) ? ((lo < 512) ? lo : 511) : -1;
        }
        __syncthreads();
        const float4* x4 = (const float4*)x;
        float4* o4 = (float4*)out0;
        const int lane6 = tid & 63, g4 = tid >> 6;
        #pragma unroll 4
        for (int rr = 0; rr < 16; ++rr) {
            int r = rr * 4 + g4;
            int idx = sidx[r];
            float4 v = make_float4(0.f, 0.f, 0.f, 0.f);
            if (idx >= 0) v = x4[((size_t)(b * 512 + idx)) * 64 + lane6];
            o4[((size_t)(b * 2304 + t0o + r)) * 64 + lane6] = v;
        }
        return;
    }

    // ---------- conv path ----------
    const int w_ = tid >> 6, lane = tid & 63;
    const int q = lane >> 4, col = lane & 15;
    const int b  = blockIdx.x >> 4;
    const int t0 = (blockIdx.x & 15) << 5;

    floatx4 acc[2][4] = {};
    const ushort* xbb = xb + ((size_t)b * 514 + t0) * 256;
    const ushort* wpw = wpb + w_ * 4096 + lane * 8;    // wave's B rows, per-lane 16 B
    ushort* buf0 = &Bws[w_][0][0];
    ushort* buf1 = &Bws[w_][1][0];

    short8 afb[2][2][2];                               // [parity][mi][kh]

    // prologue: issue step-0 batch (8 DMA + 4 A-loads)
    #pragma unroll
    for (int i = 0; i < 8; ++i) cp16(wpw + i * 512, buf0 + i * 512);
    #pragma unroll
    for (int mi = 0; mi < 2; ++mi)
        #pragma unroll
        for (int kh = 0; kh < 2; ++kh)
            afb[0][mi][kh] = *(const short8*)(xbb + (size_t)(mi * 16 + col) * 256
                                              + kh * 32 + q * 8);

    #pragma unroll
    for (int s = 0; s < 12; ++s) {
        // issue step-(s+1) batch (clamped re-issue at s=11; lands in dead buffer)
        const int sp = (s < 11) ? s + 1 : 11;
        const int krow = sp >> 2, cb = (sp & 3) << 6;
        ushort* nbuf = (s & 1) ? buf0 : buf1;
        const ushort* wsrc = wpw + (size_t)sp * 16384;
        #pragma unroll
        for (int i = 0; i < 8; ++i) cp16(wsrc + i * 512, nbuf + i * 512);
        #pragma unroll
        for (int mi = 0; mi < 2; ++mi)
            #pragma unroll
            for (int kh = 0; kh < 2; ++kh)
                afb[(s + 1) & 1][mi][kh] = *(const short8*)(xbb
                    + (size_t)(mi * 16 + col + krow) * 256 + cb + kh * 32 + q * 8);
        // wait for step-s batch only (12 newest ops may stay in flight)
        asm volatile("s_waitcnt vmcnt(12)" ::: "memory");
        const ushort* cbuf = (s & 1) ? buf1 : buf0;
        short8 bfr[4][2];
        #pragma unroll
        for (int ni = 0; ni < 4; ++ni)
            #pragma unroll
            for (int kh = 0; kh < 2; ++kh)
                bfr[ni][kh] = *(const short8*)((const char*)cbuf
                    + (ni * 16 + col) * 128 + (((kh * 4 + q) ^ (col & 7)) << 4));
        #pragma unroll
        for (int kh = 0; kh < 2; ++kh)
            #pragma unroll
            for (int mi = 0; mi < 2; ++mi)
                #pragma unroll
                for (int ni = 0; ni < 4; ++ni)
                    acc[mi][ni] = __builtin_amdgcn_mfma_f32_16x16x32_bf16(
                        afb[s & 1][mi][kh], bfr[ni][kh], acc[mi][ni], 0, 0, 0);
    }

    // ---- epilogue: bias + per-row LN stats from registers ----
    const int base_c = w_ * 64;
    float cb4[4], gm4[4], bt4[4];
    #pragma unroll
    for (int ni = 0; ni < 4; ++ni) {
        cb4[ni] = cbias[base_c + ni * 16 + col];
        gm4[ni] = gamma[base_c + ni * 16 + col];
        bt4[ni] = beta [base_c + ni * 16 + col];
    }
    float rsum[2][4] = {}, rsq[2][4] = {};
    #pragma unroll
    for (int mi = 0; mi < 2; ++mi)
        #pragma unroll
        for (int ni = 0; ni < 4; ++ni)
            #pragma unroll
            for (int r = 0; r < 4; ++r) {
                float v = acc[mi][ni][r] + cb4[ni];
                acc[mi][ni][r] = v;
                rsum[mi][r] += v;
                rsq [mi][r] += v * v;
            }
    #pragma unroll
    for (int mi = 0; mi < 2; ++mi)
        #pragma unroll
        for (int r = 0; r < 4; ++r) {
            float s = rsum[mi][r], ss = rsq[mi][r];
            #pragma unroll
            for (int d = 8; d > 0; d >>= 1) {
                s  += __shfl_down(s,  d, 16);
                ss += __shfl_down(ss, d, 16);
            }
            if (col == 0) {
                sum_s[w_][mi * 16 + q * 4 + r] = s;
                sq_s [w_][mi * 16 + q * 4 + r] = ss;
            }
        }
    __syncthreads();
    if (tid < 32) {
        float s  = sum_s[0][tid] + sum_s[1][tid] + sum_s[2][tid] + sum_s[3][tid];
        float ss = sq_s [0][tid] + sq_s [1][tid] + sq_s [2][tid] + sq_s [3][tid];
        float mu = s * (1.f / 256.f);
        mu_s[tid] = mu;
        rs_s[tid] = rsqrtf(ss * (1.f / 256.f) - mu * mu + 1e-5f);
    }
    __syncthreads();

    if (!IS_CONV2) {
        #pragma unroll
        for (int mi = 0; mi < 2; ++mi)
            #pragma unroll
            for (int ni = 0; ni < 4; ++ni)
                #pragma unroll
                for (int r = 0; r < 4; ++r) {
                    int row = mi * 16 + q * 4 + r;
                    float v = (acc[mi][ni][r] - mu_s[row]) * rs_s[row] * gm4[ni] + bt4[ni];
                    outb[((size_t)b * 514 + t0 + row + 1) * 256 + base_c + ni * 16 + col]
                        = f2bf(fmaxf(v, 0.f));
                }
    } else {
        float lw4[4];
        #pragma unroll
        for (int ni = 0; ni < 4; ++ni) lw4[ni] = lw[base_c + ni * 16 + col];
        float dsum[2][4] = {};
        #pragma unroll
        for (int mi = 0; mi < 2; ++mi)
            #pragma unroll
            for (int ni = 0; ni < 4; ++ni)
                #pragma unroll
                for (int r = 0; r < 4; ++r) {
                    int row = mi * 16 + q * 4 + r;
                    float v = (acc[mi][ni][r] - mu_s[row]) * rs_s[row] * gm4[ni] + bt4[ni];
                    dsum[mi][r] += fmaxf(v, 0.f) * lw4[ni];
                }
        #pragma unroll
        for (int mi = 0; mi < 2; ++mi)
            #pragma unroll
            for (int r = 0; r < 4; ++r) {
                float s = dsum[mi][r];
                #pragma unroll
                for (int d = 8; d > 0; d >>= 1) s += __shfl_down(s, d, 16);
                if (col == 0) sum_s[w_][mi * 16 + q * 4 + r] = s;
            }
        __syncthreads();
        if (tid < 32)
            durp[b * 512 + t0 + tid] = fmaxf(sum_s[0][tid] + sum_s[1][tid]
                                           + sum_s[2][tid] + sum_s[3][tid] + lb[0], 0.f);
    }
}

extern "C" void kernel_launch(void* const* d_in, const int* in_sizes, int n_in,
                              void* d_out, int out_size, void* d_ws, size_t ws_size,
                              hipStream_t stream) {
    const float* x      = (const float*)d_in[0];
    const int*   target = (const int*)  d_in[1];
    const float* c1w = (const float*)d_in[3];
    const float* c1b = (const float*)d_in[4];
    const float* g1  = (const float*)d_in[5];
    const float* b1  = (const float*)d_in[6];
    const float* c2w = (const float*)d_in[7];
    const float* c2b = (const float*)d_in[8];
    const float* g2  = (const float*)d_in[9];
    const float* b2  = (const float*)d_in[10];
    const float* lw  = (const float*)d_in[11];
    const float* lb  = (const float*)d_in[12];

    const size_t PADEL = (size_t)32 * 514 * 256;
    ushort* xb   = (ushort*)d_ws;
    ushort* h1b  = xb + PADEL;
    ushort* w1pb = h1b + PADEL;
    ushort* w2pb = w1pb + 196608;

    float* out0 = (float*)d_out;                  // [32, 2304, 256]
    float* durp = out0 + (size_t)32 * 2304 * 256; // [32, 512]

    prep_kernel<<<5648, 256, 0, stream>>>(x, c1w, c2w, xb, h1b, w1pb, w2pb);
    conv_mfma_kernel<false><<<512, 256, 0, stream>>>(
        xb, w1pb, c1b, g1, b1, nullptr, nullptr, h1b, nullptr,
        nullptr, nullptr, nullptr);
    conv_mfma_kernel<true><<<512 + 1152, 256, 0, stream>>>(
        h1b, w2pb, c2b, g2, b2, lw, lb, nullptr, durp,
        x, target, out0);
}

// Round 7
// 157.761 us; speedup vs baseline: 1.8381x; 1.0685x over previous
//
#include <hip/hip_runtime.h>

typedef __attribute__((ext_vector_type(8))) short short8;   // 8 bf16 = 4 VGPRs
typedef __attribute__((ext_vector_type(4))) float floatx4;  // MFMA acc

typedef __attribute__((address_space(3))) unsigned int lds_u32;
typedef __attribute__((address_space(1))) const unsigned int glb_u32;

static __device__ __forceinline__ unsigned short f2bf(float f) {
    unsigned int u = __float_as_uint(f);
    return (unsigned short)((u + 0x7FFFu + ((u >> 16) & 1u)) >> 16);   // RNE
}
// async 16-B global->LDS DMA; LDS dest = wave-uniform base + lane*16
static __device__ __forceinline__ void cp16(const ushort* g, ushort* l) {
    __builtin_amdgcn_global_load_lds((glb_u32*)g, (lds_u32*)l, 16, 0, 0);
}

// ---- prep ----
// blocks [0,4112): x -> bf16 padded xb [B][514][256] (+ zero h1b pad rows)
// blocks [4112,5648): w[F][C][3] -> wpb [24 steps(BK=32)][256 f][32 kk], with
//   quad swizzle: dest quad jd (16B) of row f holds source k-quad jd^((f>>1)&3).
__global__ __launch_bounds__(256)
void prep_kernel(const float* __restrict__ x, const float* __restrict__ w1,
                 const float* __restrict__ w2,
                 ushort* __restrict__ xb, ushort* __restrict__ h1b,
                 ushort* __restrict__ w1pb, ushort* __restrict__ w2pb)
{
    const int blk = blockIdx.x, tid = threadIdx.x;
    if (blk < 4112) {
        const int r = blk * 4 + (tid >> 6);
        const int c = (tid & 63) * 4;
        const int b = r / 514, tp = r % 514;
        ushort4 o;
        if (tp >= 1 && tp <= 512) {
            float4 v = *(const float4*)(x + ((size_t)(b * 512 + tp - 1) * 256 + c));
            o.x = f2bf(v.x); o.y = f2bf(v.y); o.z = f2bf(v.z); o.w = f2bf(v.w);
        } else {
            o.x = o.y = o.z = o.w = 0;
            *(ushort4*)(h1b + (size_t)r * 256 + c) = o;   // zero h1b pad rows
        }
        *(ushort4*)(xb + (size_t)r * 256 + c) = o;
    } else {
        const bool second = blk >= 4880;
        const int e = (blk - (second ? 4880 : 4112)) * 256 + tid;  // dest index
        const float* w = second ? w2 : w1;
        ushort* wpb = second ? w2pb : w1pb;
        const int f = e / 768, j = e % 768;
        const int s = j >> 5, kk = j & 31;
        const int jd = kk >> 3, o = kk & 7;
        const int jsrc = s * 32 + (jd ^ ((f >> 1) & 3)) * 8 + o;   // source K index
        const int c = jsrc & 255, kr = jsrc >> 8;
        wpb[s * 8192 + f * 32 + kk] = f2bf(w[f * 768 + c * 3 + kr]);
    }
}

// ---- conv1d(K=3) MFMA GEMM: A-resident + 4-deep B ring, fine-grained vmcnt ----
// Grid: 256 conv blocks (+576 gather blocks for IS_CONV2). Block 512 thr (8 waves).
// Tile 64 rows x 256 cols; wave w = 64 rows x cols [w*32,(w+1)*32). K=768 = 24xBK32.
// A (66 rows x 512 B, quad-swizzled) staged ONCE (33 KB). B streamed through a
// 4x16 KB LDS ring, 2-step lookahead, per-step s_waitcnt vmcnt(2) + raw s_barrier
// (never vmcnt(0) until the last step) -> ~32 KB/CU of staging in flight.
template<bool IS_CONV2>
__global__ __launch_bounds__(512, 2)
void conv_mfma_kernel(const ushort* __restrict__ inb_g,  // [B][514][256] bf16 padded
                      const ushort* __restrict__ wpb,    // [24][256][32] bf16 swizzled
                      const float* __restrict__ cbias,
                      const float* __restrict__ gamma, const float* __restrict__ beta,
                      const float* __restrict__ lw, const float* __restrict__ lb,
                      ushort* __restrict__ outb,         // conv1: h1b
                      float* __restrict__ durp,          // conv2: [B][512]
                      const float* __restrict__ x,       // conv2 gather path
                      const int* __restrict__ target,
                      float* __restrict__ out0)          // [B][2304][256]
{
    __shared__ ushort As[66 * 256];     // 33 KB: 66 rows x 512 B, 32-quad swizzle
    __shared__ ushort Bs[4 * 8192];     // 64 KB: ring of 4 x (256 rows x 64 B)
    __shared__ float sum_s[8][64], sq_s[8][64], mu_s[64], rs_s[64];
    __shared__ int cum[512], sidx[128];

    const int tid = threadIdx.x;

    if (IS_CONV2 && blockIdx.x >= 256) {
        // ---------- gather: 576 blocks x 128 output rows ----------
        const int g = blockIdx.x - 256;
        const int b = g / 18, seg = g % 18;
        cum[tid] = target[b * 512 + tid];
        __syncthreads();
        for (int off = 1; off < 512; off <<= 1) {
            int v = (tid >= off) ? cum[tid - off] : 0;
            __syncthreads();
            cum[tid] += v;
            __syncthreads();
        }
        const int total = cum[511];
        if (tid < 128) {
            int t = seg * 128 + tid;
            int lo = 0, hi = 512;
            while (lo < hi) {
                int mid = (lo + hi) >> 1;
                if (cum[mid] <= t) lo = mid + 1; else hi = mid;
            }
            sidx[tid] = (t < total) ? ((lo < 512) ? lo : 511) : -1;
        }
        __syncthreads();
        const float4* x4 = (const float4*)x;
        float4* o4 = (float4*)out0;
        const int lane6 = tid & 63, g8 = tid >> 6;
        #pragma unroll 4
        for (int it = 0; it < 16; ++it) {
            int r = it * 8 + g8;
            int idx = sidx[r];
            float4 v = make_float4(0.f, 0.f, 0.f, 0.f);
            if (idx >= 0) v = x4[((size_t)(b * 512 + idx)) * 64 + lane6];
            o4[((size_t)(b * 2304 + seg * 128 + r)) * 64 + lane6] = v;
        }
        return;
    }

    // ---------- conv path ----------
    const int w_ = tid >> 6, lane = tid & 63;
    const int q = lane >> 4, col = lane & 15;
    const int b  = blockIdx.x >> 3;
    const int t0 = (blockIdx.x & 7) << 6;

    const ushort* inB = inb_g + (size_t)b * 514 * 256;

    // ---- stage A once: 33 chunks of 1 KB (2 rows), source-quad swizzled ----
    #pragma unroll
    for (int i = 0; i < 4; ++i) {
        const int ch = w_ + i * 8;
        const int ri = 2 * ch + (lane >> 5);
        const int jd = lane & 31;
        const int js = (jd & 24) | ((jd & 7) ^ (ri & 7));
        cp16(inB + (size_t)(t0 + ri) * 256 + js * 8, As + ch * 512);
    }
    if (w_ == 0) {
        const int ri = 64 + (lane >> 5);
        const int jd = lane & 31;
        const int js = (jd & 24) | ((jd & 7) ^ (ri & 7));
        cp16(inB + (size_t)(t0 + ri) * 256 + js * 8, As + 32 * 512);
    }
    // ---- B ring prologue: steps 0,1 (2 cp16/thread each) ----
    #pragma unroll
    for (int s = 0; s < 2; ++s)
        #pragma unroll
        for (int i = 0; i < 2; ++i)
            cp16(wpb + s * 8192 + i * 4096 + w_ * 512 + lane * 8,
                 Bs + s * 8192 + i * 4096 + w_ * 512);

    floatx4 acc[4][2] = {};

    #pragma unroll
    for (int s = 0; s < 24; ++s) {
        // wait: step-s staging complete; step-(s+1)'s 2 ops stay in flight
        if (s < 23) asm volatile("s_waitcnt vmcnt(2)" ::: "memory");
        else        asm volatile("s_waitcnt vmcnt(0)" ::: "memory");
        __builtin_amdgcn_s_barrier();

        const int krow = s >> 3, kb = s & 7;
        const ushort* bb = Bs + (s & 3) * 8192;
        short8 af[4], bf[2];
        #pragma unroll
        for (int mi = 0; mi < 4; ++mi) {
            const int ri = mi * 16 + col + krow;
            const int jq = kb * 4 + q;
            const int js = (jq & 24) | ((jq & 7) ^ (ri & 7));
            af[mi] = *(const short8*)(As + ri * 256 + js * 8);
        }
        #pragma unroll
        for (int ni = 0; ni < 2; ++ni) {
            const int brow = w_ * 32 + ni * 16 + col;
            const int jd = q ^ ((brow >> 1) & 3);
            bf[ni] = *(const short8*)(bb + brow * 32 + jd * 8);
        }
        // issue step s+2 into ring slot (s+2)&3 (last read 2 barriers ago - safe)
        if (s + 2 < 24) {
            const int sp = s + 2;
            #pragma unroll
            for (int i = 0; i < 2; ++i)
                cp16(wpb + sp * 8192 + i * 4096 + w_ * 512 + lane * 8,
                     Bs + (sp & 3) * 8192 + i * 4096 + w_ * 512);
        }
        #pragma unroll
        for (int mi = 0; mi < 4; ++mi)
            #pragma unroll
            for (int ni = 0; ni < 2; ++ni)
                acc[mi][ni] = __builtin_amdgcn_mfma_f32_16x16x32_bf16(
                    af[mi], bf[ni], acc[mi][ni], 0, 0, 0);
    }
    __syncthreads();

    // ---- epilogue: bias + LN stats (row = mi*16 + q*4 + r, col = w_*32+ni*16+col) ----
    const int bc0 = w_ * 32;
    float cb2[2], gm2[2], bt2[2];
    #pragma unroll
    for (int ni = 0; ni < 2; ++ni) {
        cb2[ni] = cbias[bc0 + ni * 16 + col];
        gm2[ni] = gamma[bc0 + ni * 16 + col];
        bt2[ni] = beta [bc0 + ni * 16 + col];
    }
    float rsum[4][4] = {}, rsq[4][4] = {};
    #pragma unroll
    for (int mi = 0; mi < 4; ++mi)
        #pragma unroll
        for (int ni = 0; ni < 2; ++ni)
            #pragma unroll
            for (int r = 0; r < 4; ++r) {
                float v = acc[mi][ni][r] + cb2[ni];
                acc[mi][ni][r] = v;
                rsum[mi][r] += v;
                rsq [mi][r] += v * v;
            }
    #pragma unroll
    for (int mi = 0; mi < 4; ++mi)
        #pragma unroll
        for (int r = 0; r < 4; ++r) {
            float s = rsum[mi][r], ss = rsq[mi][r];
            #pragma unroll
            for (int d = 8; d > 0; d >>= 1) {
                s  += __shfl_down(s,  d, 16);
                ss += __shfl_down(ss, d, 16);
            }
            if (col == 0) {
                sum_s[w_][mi * 16 + q * 4 + r] = s;
                sq_s [w_][mi * 16 + q * 4 + r] = ss;
            }
        }
    __syncthreads();
    if (tid < 64) {
        float s = 0.f, ss = 0.f;
        #pragma unroll
        for (int wv = 0; wv < 8; ++wv) { s += sum_s[wv][tid]; ss += sq_s[wv][tid]; }
        float mu = s * (1.f / 256.f);
        mu_s[tid] = mu;
        rs_s[tid] = rsqrtf(ss * (1.f / 256.f) - mu * mu + 1e-5f);
    }
    __syncthreads();

    if (!IS_CONV2) {
        #pragma unroll
        for (int mi = 0; mi < 4; ++mi)
            #pragma unroll
            for (int ni = 0; ni < 2; ++ni)
                #pragma unroll
                for (int r = 0; r < 4; ++r) {
                    const int row = mi * 16 + q * 4 + r;
                    float v = (acc[mi][ni][r] - mu_s[row]) * rs_s[row] * gm2[ni] + bt2[ni];
                    outb[((size_t)b * 514 + t0 + row + 1) * 256 + bc0 + ni * 16 + col]
                        = f2bf(fmaxf(v, 0.f));
                }
    } else {
        float lw2[2];
        #pragma unroll
        for (int ni = 0; ni < 2; ++ni) lw2[ni] = lw[bc0 + ni * 16 + col];
        float dsum[4][4] = {};
        #pragma unroll
        for (int mi = 0; mi < 4; ++mi)
            #pragma unroll
            for (int ni = 0; ni < 2; ++ni)
                #pragma unroll
                for (int r = 0; r < 4; ++r) {
                    const int row = mi * 16 + q * 4 + r;
                    float v = (acc[mi][ni][r] - mu_s[row]) * rs_s[row] * gm2[ni] + bt2[ni];
                    dsum[mi][r] += fmaxf(v, 0.f) * lw2[ni];
                }
        #pragma unroll
        for (int mi = 0; mi < 4; ++mi)
            #pragma unroll
            for (int r = 0; r < 4; ++r) {
                float s = dsum[mi][r];
                #pragma unroll
                for (int d = 8; d > 0; d >>= 1) s += __shfl_down(s, d, 16);
                if (col == 0) sum_s[w_][mi * 16 + q * 4 + r] = s;
            }
        __syncthreads();
        if (tid < 64) {
            float s = 0.f;
            #pragma unroll
            for (int wv = 0; wv < 8; ++wv) s += sum_s[wv][tid];
            durp[b * 512 + t0 + tid] = fmaxf(s + lb[0], 0.f);
        }
    }
}

extern "C" void kernel_launch(void* const* d_in, const int* in_sizes, int n_in,
                              void* d_out, int out_size, void* d_ws, size_t ws_size,
                              hipStream_t stream) {
    const float* x      = (const float*)d_in[0];
    const int*   target = (const int*)  d_in[1];
    const float* c1w = (const float*)d_in[3];
    const float* c1b = (const float*)d_in[4];
    const float* g1  = (const float*)d_in[5];
    const float* b1  = (const float*)d_in[6];
    const float* c2w = (const float*)d_in[7];
    const float* c2b = (const float*)d_in[8];
    const float* g2  = (const float*)d_in[9];
    const float* b2  = (const float*)d_in[10];
    const float* lw  = (const float*)d_in[11];
    const float* lb  = (const float*)d_in[12];

    const size_t PADEL = (size_t)32 * 514 * 256;
    ushort* xb   = (ushort*)d_ws;
    ushort* h1b  = xb + PADEL;
    ushort* w1pb = h1b + PADEL;
    ushort* w2pb = w1pb + 196608;

    float* out0 = (float*)d_out;                  // [32, 2304, 256]
    float* durp = out0 + (size_t)32 * 2304 * 256; // [32, 512]

    prep_kernel<<<5648, 256, 0, stream>>>(x, c1w, c2w, xb, h1b, w1pb, w2pb);
    conv_mfma_kernel<false><<<256, 512, 0, stream>>>(
        xb, w1pb, c1b, g1, b1, nullptr, nullptr, h1b, nullptr,
        nullptr, nullptr, nullptr);
    conv_mfma_kernel<true><<<256 + 576, 512, 0, stream>>>(
        h1b, w2pb, c2b, g2, b2, lw, lb, nullptr, durp,
        x, target, out0);
}

// Round 8
// 146.569 us; speedup vs baseline: 1.9784x; 1.0764x over previous
//
#include <hip/hip_runtime.h>

typedef __attribute__((ext_vector_type(8))) short short8;   // 8 bf16 = 4 VGPRs
typedef __attribute__((ext_vector_type(4))) float floatx4;  // MFMA acc

typedef __attribute__((address_space(3))) unsigned int lds_u32;
typedef __attribute__((address_space(1))) const unsigned int glb_u32;

static __device__ __forceinline__ unsigned short f2bf(float f) {
    unsigned int u = __float_as_uint(f);
    return (unsigned short)((u + 0x7FFFu + ((u >> 16) & 1u)) >> 16);   // RNE
}
// async 16-B global->LDS DMA; LDS dest = wave-uniform base + lane*16
static __device__ __forceinline__ void cp16(const ushort* g, ushort* l) {
    __builtin_amdgcn_global_load_lds((glb_u32*)g, (lds_u32*)l, 16, 0, 0);
}

// ---- prep: x->bf16 padded [B][514][256]; w[F][C][3] -> swizzled [12][256][64] ----
// blocks [0,4112): x-convert;  [4112,4880): w1;  [4880,5648): w2
__global__ __launch_bounds__(256)
void prep_kernel(const float* __restrict__ x, const float* __restrict__ w1,
                 const float* __restrict__ w2,
                 ushort* __restrict__ xb, ushort* __restrict__ h1b,
                 ushort* __restrict__ w1pb, ushort* __restrict__ w2pb)
{
    const int blk = blockIdx.x, tid = threadIdx.x;
    if (blk < 4112) {
        const int r = blk * 4 + (tid >> 6);
        const int c = (tid & 63) * 4;
        const int b = r / 514, tp = r % 514;
        ushort4 o;
        if (tp >= 1 && tp <= 512) {
            float4 v = *(const float4*)(x + ((size_t)(b * 512 + tp - 1) * 256 + c));
            o.x = f2bf(v.x); o.y = f2bf(v.y); o.z = f2bf(v.z); o.w = f2bf(v.w);
        } else {
            o.x = o.y = o.z = o.w = 0;
            *(ushort4*)(h1b + (size_t)r * 256 + c) = o;   // zero h1b pad rows
        }
        *(ushort4*)(xb + (size_t)r * 256 + c) = o;
    } else {
        const bool second = blk >= 4880;
        const int e = (blk - (second ? 4880 : 4112)) * 256 + tid;
        const float* w = second ? w2 : w1;
        ushort* wpb = second ? w2pb : w1pb;
        const int f = e / 768, j = e % 768;
        const int c = j & 255, kr = j >> 8;
        const int s = j >> 6, kk = j & 63;
        wpb[s * 16384 + f * 64 + (((kk >> 3) ^ (f & 7)) << 3) + (kk & 7)]
            = f2bf(w[f * 768 + c * 3 + kr]);
    }
}

// ---- conv1d(K=3) MFMA GEMM, R4 structure + K-step stagger + XCD b-swizzle ----
// Grid: 512 conv blocks (+1152 gather blocks when IS_CONV2). Block 256 thr.
// Tile 32 rows x 256 cols; K=768 as 12 steps of BK=64, visited in rotated order
// rot = blockIdx%12 so concurrent blocks read DIFFERENT weight chunks (kills the
// same-line L2 serialization). b = blockIdx%32 co-locates a batch's 16 blocks on
// one XCD (blockIdx%8 round-robin) for A-tile L2 residency.
template<bool IS_CONV2>
__global__ __launch_bounds__(256, 2)
void conv_mfma_kernel(const ushort* __restrict__ xb,   // [B][514][256] bf16 padded
                      const ushort* __restrict__ wpb,  // [12][256][64] bf16 swizzled
                      const float* __restrict__ cbias,
                      const float* __restrict__ gamma, const float* __restrict__ beta,
                      const float* __restrict__ lw, const float* __restrict__ lb,
                      ushort* __restrict__ outb,       // conv1: h1b
                      float* __restrict__ durp,        // conv2: [B][512]
                      const float* __restrict__ x,     // conv2 gather path
                      const int* __restrict__ target,
                      float* __restrict__ out0)        // [B][2304][256]
{
    __shared__ ushort As[32 * 64];    // 4 KB, quad-swizzled
    __shared__ ushort Bs[256 * 64];   // 32 KB, quad-swizzled
    __shared__ float sum_s[4][32], sq_s[4][32], mu_s[32], rs_s[32];
    __shared__ int cum[512], ps[256], sidx[64];       // gather path only

    const int tid = threadIdx.x;

    if (IS_CONV2 && blockIdx.x >= 512) {
        // ---------- gather: 1152 blocks, 64 output rows each ----------
        const int bg = blockIdx.x - 512;
        const int b = bg / 36, t0o = (bg % 36) * 64;
        const int v0 = target[b * 512 + 2 * tid];
        const int v1 = target[b * 512 + 2 * tid + 1];
        ps[tid] = v0 + v1;
        __syncthreads();
        for (int off = 1; off < 256; off <<= 1) {
            int t = (tid >= off) ? ps[tid - off] : 0;
            __syncthreads();
            ps[tid] += t;
            __syncthreads();
        }
        const int excl = tid ? ps[tid - 1] : 0;
        cum[2 * tid]     = excl + v0;
        cum[2 * tid + 1] = excl + v0 + v1;
        __syncthreads();
        const int total = cum[511];
        if (tid < 64) {
            int t = t0o + tid;
            int lo = 0, hi = 512;
            while (lo < hi) {
                int mid = (lo + hi) >> 1;
                if (cum[mid] <= t) lo = mid + 1; else hi = mid;
            }
            sidx[tid] = (t < total) ? ((lo < 512) ? lo : 511) : -1;
        }
        __syncthreads();
        const float4* x4 = (const float4*)x;
        float4* o4 = (float4*)out0;
        const int lane6 = tid & 63, g4 = tid >> 6;
        #pragma unroll 4
        for (int rr = 0; rr < 16; ++rr) {
            int r = rr * 4 + g4;
            int idx = sidx[r];
            float4 v = make_float4(0.f, 0.f, 0.f, 0.f);
            if (idx >= 0) v = x4[((size_t)(b * 512 + idx)) * 64 + lane6];
            o4[((size_t)(b * 2304 + t0o + r)) * 64 + lane6] = v;
        }
        return;
    }

    // ---------- conv path ----------
    const int w_ = tid >> 6, lane = tid & 63;
    const int q = lane >> 4, col = lane & 15;
    const int b  = blockIdx.x & 31;                    // XCD-local batches
    const int t0 = (blockIdx.x >> 5) << 5;
    const int rot = blockIdx.x % 12;                   // K-step stagger

    floatx4 acc[2][4] = {};
    const ushort* xbb = xb + (size_t)b * 514 * 256;
    const int arow = tid >> 3, aquad = (tid & 7) ^ (arow & 7);
    ushort* AsW = As + (size_t)w_ * 512;               // wave-uniform LDS bases
    ushort* BsW = Bs + (size_t)w_ * 512;

    for (int s = 0; s < 12; ++s) {
        int se = s + rot; if (se >= 12) se -= 12;      // rotated chunk order
        const int krow = se >> 2, cbo = (se & 3) << 6;
        cp16(xbb + (size_t)(t0 + krow + arow) * 256 + cbo + aquad * 8, AsW);
        const ushort* wsrc = wpb + (size_t)se * 16384 + w_ * 512 + lane * 8;
        #pragma unroll
        for (int i = 0; i < 8; ++i) cp16(wsrc + i * 2048, BsW + i * 2048);
        __syncthreads();
        short8 af[2][2], bf[4][2];
        #pragma unroll
        for (int mi = 0; mi < 2; ++mi)
            #pragma unroll
            for (int kh = 0; kh < 2; ++kh)
                af[mi][kh] = *(const short8*)((const char*)As
                    + (mi * 16 + col) * 128 + (((kh * 4 + q) ^ (col & 7)) * 16));
        #pragma unroll
        for (int ni = 0; ni < 4; ++ni)
            #pragma unroll
            for (int kh = 0; kh < 2; ++kh)
                bf[ni][kh] = *(const short8*)((const char*)Bs
                    + (w_ * 64 + ni * 16 + col) * 128 + (((kh * 4 + q) ^ (col & 7)) * 16));
        #pragma unroll
        for (int kh = 0; kh < 2; ++kh)
            #pragma unroll
            for (int mi = 0; mi < 2; ++mi)
                #pragma unroll
                for (int ni = 0; ni < 4; ++ni)
                    acc[mi][ni] = __builtin_amdgcn_mfma_f32_16x16x32_bf16(
                        af[mi][kh], bf[ni][kh], acc[mi][ni], 0, 0, 0);
        __syncthreads();
    }

    // ---- epilogue: bias + per-row LN stats from registers ----
    const int base_c = w_ * 64;
    float cb4[4], gm4[4], bt4[4];
    #pragma unroll
    for (int ni = 0; ni < 4; ++ni) {
        cb4[ni] = cbias[base_c + ni * 16 + col];
        gm4[ni] = gamma[base_c + ni * 16 + col];
        bt4[ni] = beta [base_c + ni * 16 + col];
    }
    float rsum[2][4] = {}, rsq[2][4] = {};
    #pragma unroll
    for (int mi = 0; mi < 2; ++mi)
        #pragma unroll
        for (int ni = 0; ni < 4; ++ni)
            #pragma unroll
            for (int r = 0; r < 4; ++r) {
                float v = acc[mi][ni][r] + cb4[ni];
                acc[mi][ni][r] = v;
                rsum[mi][r] += v;
                rsq [mi][r] += v * v;
            }
    #pragma unroll
    for (int mi = 0; mi < 2; ++mi)
        #pragma unroll
        for (int r = 0; r < 4; ++r) {
            float s = rsum[mi][r], ss = rsq[mi][r];
            #pragma unroll
            for (int d = 8; d > 0; d >>= 1) {
                s  += __shfl_down(s,  d, 16);
                ss += __shfl_down(ss, d, 16);
            }
            if (col == 0) {
                sum_s[w_][mi * 16 + q * 4 + r] = s;
                sq_s [w_][mi * 16 + q * 4 + r] = ss;
            }
        }
    __syncthreads();
    if (tid < 32) {
        float s  = sum_s[0][tid] + sum_s[1][tid] + sum_s[2][tid] + sum_s[3][tid];
        float ss = sq_s [0][tid] + sq_s [1][tid] + sq_s [2][tid] + sq_s [3][tid];
        float mu = s * (1.f / 256.f);
        mu_s[tid] = mu;
        rs_s[tid] = rsqrtf(ss * (1.f / 256.f) - mu * mu + 1e-5f);
    }
    __syncthreads();

    if (!IS_CONV2) {
        #pragma unroll
        for (int mi = 0; mi < 2; ++mi)
            #pragma unroll
            for (int ni = 0; ni < 4; ++ni)
                #pragma unroll
                for (int r = 0; r < 4; ++r) {
                    int row = mi * 16 + q * 4 + r;
                    float v = (acc[mi][ni][r] - mu_s[row]) * rs_s[row] * gm4[ni] + bt4[ni];
                    outb[((size_t)b * 514 + t0 + row + 1) * 256 + base_c + ni * 16 + col]
                        = f2bf(fmaxf(v, 0.f));
                }
    } else {
        float lw4[4];
        #pragma unroll
        for (int ni = 0; ni < 4; ++ni) lw4[ni] = lw[base_c + ni * 16 + col];
        float dsum[2][4] = {};
        #pragma unroll
        for (int mi = 0; mi < 2; ++mi)
            #pragma unroll
            for (int ni = 0; ni < 4; ++ni)
                #pragma unroll
                for (int r = 0; r < 4; ++r) {
                    int row = mi * 16 + q * 4 + r;
                    float v = (acc[mi][ni][r] - mu_s[row]) * rs_s[row] * gm4[ni] + bt4[ni];
                    dsum[mi][r] += fmaxf(v, 0.f) * lw4[ni];
                }
        #pragma unroll
        for (int mi = 0; mi < 2; ++mi)
            #pragma unroll
            for (int r = 0; r < 4; ++r) {
                float s = dsum[mi][r];
                #pragma unroll
                for (int d = 8; d > 0; d >>= 1) s += __shfl_down(s, d, 16);
                if (col == 0) sum_s[w_][mi * 16 + q * 4 + r] = s;
            }
        __syncthreads();
        if (tid < 32)
            durp[b * 512 + t0 + tid] = fmaxf(sum_s[0][tid] + sum_s[1][tid]
                                           + sum_s[2][tid] + sum_s[3][tid] + lb[0], 0.f);
    }
}

extern "C" void kernel_launch(void* const* d_in, const int* in_sizes, int n_in,
                              void* d_out, int out_size, void* d_ws, size_t ws_size,
                              hipStream_t stream) {
    const float* x      = (const float*)d_in[0];
    const int*   target = (const int*)  d_in[1];
    const float* c1w = (const float*)d_in[3];
    const float* c1b = (const float*)d_in[4];
    const float* g1  = (const float*)d_in[5];
    const float* b1  = (const float*)d_in[6];
    const float* c2w = (const float*)d_in[7];
    const float* c2b = (const float*)d_in[8];
    const float* g2  = (const float*)d_in[9];
    const float* b2  = (const float*)d_in[10];
    const float* lw  = (const float*)d_in[11];
    const float* lb  = (const float*)d_in[12];

    const size_t PADEL = (size_t)32 * 514 * 256;
    ushort* xb   = (ushort*)d_ws;
    ushort* h1b  = xb + PADEL;
    ushort* w1pb = h1b + PADEL;
    ushort* w2pb = w1pb + 196608;

    float* out0 = (float*)d_out;                  // [32, 2304, 256]
    float* durp = out0 + (size_t)32 * 2304 * 256; // [32, 512]

    prep_kernel<<<5648, 256, 0, stream>>>(x, c1w, c2w, xb, h1b, w1pb, w2pb);
    conv_mfma_kernel<false><<<512, 256, 0, stream>>>(
        xb, w1pb, c1b, g1, b1, nullptr, nullptr, h1b, nullptr,
        nullptr, nullptr, nullptr);
    conv_mfma_kernel<true><<<512 + 1152, 256, 0, stream>>>(
        h1b, w2pb, c2b, g2, b2, lw, lb, nullptr, durp,
        x, target, out0);
}